// Round 7
// baseline (3317.719 us; speedup 1.0000x reference)
//
#include <hip/hip_runtime.h>
#include <stdint.h>

typedef __attribute__((ext_vector_type(8))) short short8;
typedef __attribute__((ext_vector_type(4))) short short4_;
typedef __attribute__((ext_vector_type(4))) float f4;
typedef __attribute__((ext_vector_type(4))) uint32_t u32x4;

#define B_ 64
#define T_ 512
#define E_ 512
#define H_ 512
#define GH 2048  // 4*H

static __device__ __forceinline__ uint16_t f2bf(float f) {
  uint32_t u = __builtin_bit_cast(uint32_t, f);
  uint32_t r = (u + 0x7FFFu + ((u >> 16) & 1u)) >> 16;
  return (uint16_t)r;
}
static __device__ __forceinline__ float bf2f(uint16_t b) {
  return __builtin_bit_cast(float, (uint32_t)b << 16);
}
static __device__ __forceinline__ float sigmoidf_(float x) {
  return 1.0f / (1.0f + __expf(-x));
}
static __device__ __forceinline__ float tanhf_(float x) {
  float e = __expf(-2.0f * fabsf(x));
  float t = (1.0f - e) / (1.0f + e);
  return __builtin_copysignf(t, x);
}

// ---- L3-coherent (agent) access helpers: sc0 sc1 = bypass L1+L2, coherence at L3.
// Protocol (r5-proven): producer stores -> vmcnt(0) drain -> flag store;
// consumer: poll flag -> (flag seen => data committed) -> batched loads.
static __device__ __forceinline__ int ld_flag_cc(const int* p) {
  int v;
  asm volatile("global_load_dword %0, %1, off sc0 sc1\n\ts_waitcnt vmcnt(0)"
               : "=v"(v) : "v"(p) : "memory");
  return v;
}
static __device__ __forceinline__ void ld_x4_cc(u32x4* d, const void* p) {
  asm volatile("global_load_dwordx4 %0, %1, off sc0 sc1" : "=v"(*d) : "v"(p));
}
static __device__ __forceinline__ void st_u32_cc(uint32_t* p, uint32_t v) {
  asm volatile("global_store_dword %0, %1, off sc0 sc1" :: "v"(p), "v"(v) : "memory");
}
static __device__ __forceinline__ void st_flag_cc(int* p, int v) {
  asm volatile("global_store_dword %0, %1, off sc0 sc1" :: "v"(p), "v"(v) : "memory");
}

// ---------------- prep: split W_hh fp32 -> bf16 hi + bf16 lo
__global__ void k_prep(const float* __restrict__ Whh, uint16_t* __restrict__ Whi_g,
                       uint16_t* __restrict__ Wlo_g) {
  int i = blockIdx.x * 256 + threadIdx.x;
  float w = Whh[i];
  uint16_t hi = f2bf(w);
  Whi_g[i] = hi;
  Wlo_g[i] = f2bf(w - bf2f(hi));
}

// ---------------- init: h0 -> packed (hi | lo<<16) parity-0 buffer; zero 512 flags
__global__ void k_init(const float* __restrict__ h0, uint32_t* __restrict__ hP0,
                       int* __restrict__ flags) {
  int i = blockIdx.x * 256 + threadIdx.x;
  if (i < B_ * H_) {
    float v = h0[i];
    uint16_t hi = f2bf(v);
    uint16_t lo = f2bf(v - bf2f(hi));
    hP0[i] = (uint32_t)hi | ((uint32_t)lo << 16);
  }
  if (i < 512) flags[i] = 0;
}

// ---------------- pre-projection GEMM (verified r1-r5). Output: per-consumer blocks
// pre2[((t_rel*32 + ug)*4 + bg)*1024 + g_loc*16 + b_loc], g_loc = q*16 + u_loc.
__launch_bounds__(256)
__global__ void k_pre(const int* __restrict__ x, const float* __restrict__ emb,
                      const float* __restrict__ Wih, const float* __restrict__ bih,
                      const float* __restrict__ bhh, float* __restrict__ pre2, int t0) {
  __shared__ uint16_t As[128 * 64];
  __shared__ uint16_t Bs[128 * 64];
  const int tid = threadIdx.x;
  const int tm = blockIdx.x >> 4;
  const int tn = blockIdx.x & 15;
  const int wid = tid >> 6, lane = tid & 63;
  const int wr = wid >> 1, wc = wid & 1;

  const int arow = tid >> 1;
  const int half = tid & 1;
  const int m = tm * 128 + arow;
  const int bb = m & 63;
  const int tt = t0 + (m >> 6);
  const int xid = x[bb * T_ + tt];
  const float* asrc = emb + (size_t)xid * E_ + half * 32;
  const float* bsrc = Wih + (size_t)(tn * 128 + arow) * E_ + half * 32;

  f4 acc[4][4];
#pragma unroll
  for (int a = 0; a < 4; ++a)
#pragma unroll
    for (int b = 0; b < 4; ++b) acc[a][b] = (f4){0.f, 0.f, 0.f, 0.f};

  for (int kk = 0; kk < 8; ++kk) {
    __syncthreads();
#pragma unroll
    for (int gi = 0; gi < 4; ++gi) {
      f4 a0 = *(const f4*)(asrc + kk * 64 + gi * 8);
      f4 a1 = *(const f4*)(asrc + kk * 64 + gi * 8 + 4);
      f4 b0 = *(const f4*)(bsrc + kk * 64 + gi * 8);
      f4 b1 = *(const f4*)(bsrc + kk * 64 + gi * 8 + 4);
      short8 va, vb;
#pragma unroll
      for (int j = 0; j < 4; ++j) {
        va[j] = (short)f2bf(a0[j]); va[4 + j] = (short)f2bf(a1[j]);
        vb[j] = (short)f2bf(b0[j]); vb[4 + j] = (short)f2bf(b1[j]);
      }
      int kq = half * 4 + gi;
      *(short8*)(As + arow * 64 + (kq ^ (arow & 7)) * 8) = va;
      *(short8*)(Bs + arow * 64 + (kq ^ (arow & 7)) * 8) = vb;
    }
    __syncthreads();
#pragma unroll
    for (int ks = 0; ks < 2; ++ks) {
      short8 af[4], bfr[4];
#pragma unroll
      for (int mi = 0; mi < 4; ++mi) {
        int row = wr * 64 + mi * 16 + (lane & 15);
        int kq = ks * 4 + (lane >> 4);
        af[mi] = *(const short8*)(As + row * 64 + (kq ^ (row & 7)) * 8);
      }
#pragma unroll
      for (int ni = 0; ni < 4; ++ni) {
        int row = wc * 64 + ni * 16 + (lane & 15);
        int kq = ks * 4 + (lane >> 4);
        bfr[ni] = *(const short8*)(Bs + row * 64 + (kq ^ (row & 7)) * 8);
      }
#pragma unroll
      for (int mi = 0; mi < 4; ++mi)
#pragma unroll
        for (int ni = 0; ni < 4; ++ni)
          acc[mi][ni] = __builtin_amdgcn_mfma_f32_16x16x32_bf16(af[mi], bfr[ni], acc[mi][ni], 0, 0, 0);
    }
  }
#pragma unroll
  for (int ni = 0; ni < 4; ++ni) {
    int n = tn * 128 + wc * 64 + ni * 16 + (lane & 15);
    float bias = bih[n] + bhh[n];
    int q = n >> 9, u = n & 511;
    int ug = u >> 4, uloc = u & 15;
    int gl = q * 16 + uloc;
#pragma unroll
    for (int mi = 0; mi < 4; ++mi) {
      int mrow = tm * 128 + wr * 64 + mi * 16 + (lane >> 4) * 4;
      int trel = mrow >> 6;
      int bbr = mrow & 63;
      f4 vst;
#pragma unroll
      for (int j = 0; j < 4; ++j) vst[j] = acc[mi][ni][j] + bias;
      float* dst = pre2 + (((size_t)trel * 32 + ug) * 4 + (bbr >> 4)) * 1024 + gl * 16 + (bbr & 15);
      *(f4*)dst = vst;
    }
  }
}

// ---------------- persistent recurrence, per-WAVE flag protocol (r5 ordering,
// finer grain). 128 wgs = 4 bg x 32 ug; 1 wg/CU by LDS capacity (160 KiB).
// Producer wave: 64 packed-u32 h stores -> own vmcnt(0) -> own flag (no barrier).
// Consumer wave w: polls its 32 producer-wave flags (1 line), gathers its unit
// range [w*128,(w+1)*128) -> LDS; collective staging barrier gates MFMA on all
// 128 flags transitively (parity-overwrite race closed as in r5). Polls bounded.
__launch_bounds__(256)
__global__ void k_lstm(const float* __restrict__ pre2, const uint16_t* __restrict__ Whi_g,
                       const uint16_t* __restrict__ Wlo_g, const float* __restrict__ c0,
                       float* __restrict__ out, uint32_t* __restrict__ hP0,
                       uint32_t* __restrict__ hP1, float* __restrict__ c_state,
                       int* __restrict__ flags, int t0, int TB) {
  extern __shared__ char smem[];
  uint16_t* WhiL = (uint16_t*)smem;              // [64][512] 64 KiB
  uint16_t* WloL = (uint16_t*)(smem + 65536);    // [64][512] 64 KiB
  uint16_t* Hh   = (uint16_t*)(smem + 131072);   // [16][512] 16 KiB
  uint16_t* Hl   = (uint16_t*)(smem + 147456);   // [16][512] 16 KiB

  const int tid = threadIdx.x;
  const int bg = blockIdx.x & 3;    // batch group (16 rows)
  const int ug = blockIdx.x >> 2;   // unit group (16 units)
  const int wv = tid >> 6, lane = tid & 63;
  const int wi = lane & 15, hi4 = lane >> 4;
  const int q = wi & 3, v = wi >> 2;
  const int u = ug * 16 + wv * 4 + v;   // this lane's unit
  const int gl = q * 16 + wv * 4 + v;   // g_loc in pre2 block

  // stage W hi/lo slice (64 gate-rows x 512) into LDS, 16B-granule XOR swizzle
  for (int it = 0; it < 16; ++it) {
    int gg = it * 256 + tid;
    int r = gg >> 6, kq = gg & 63;
    int grow = (r & 3) * 512 + ug * 16 + (r >> 4) * 4 + ((r >> 2) & 3);
    short8 whi = *(const short8*)(Whi_g + (size_t)grow * 512 + kq * 8);
    short8 wlo = *(const short8*)(Wlo_g + (size_t)grow * 512 + kq * 8);
    int kqs = (kq & ~7) | ((kq & 7) ^ (r & 7));
    *(short8*)(WhiL + r * 512 + kqs * 8) = whi;
    *(short8*)(WloL + r * 512 + kqs * 8) = wlo;
  }

  f4 c_reg;
  {
    const float* csrc = (t0 == 0) ? c0 : c_state;
    const int brow = bg * 16 + hi4 * 4;
#pragma unroll
    for (int j = 0; j < 4; ++j) c_reg[j] = csrc[(size_t)(brow + j) * H_ + u];
  }
  int* fl = flags + bg * 128;           // per-bg: 128 wave-flags (idx = ug*4 + wv)
  int* myflag = fl + ug * 4 + wv;
  __syncthreads();

  for (int s = t0 + 1; s <= t0 + TB; ++s) {
    const uint32_t* hsrc = (((s - 1) & 1) ? hP1 : hP0) + (size_t)bg * 16 * 512;
    uint32_t* hdst = (s & 1) ? hP1 : hP0;

    // prefetch this wg's pre2 fragment (wg-private, plain L2 load)
    f4 accA, accB, accC;
    {
      const float* pblk = pre2 + (((size_t)(s - 1 - t0) * 32 + ug) * 4 + bg) * 1024;
      accA = *(const f4*)(pblk + gl * 16 + hi4 * 4);
      accB = (f4){0.f, 0.f, 0.f, 0.f};
      accC = accB;
    }

    // wave w waits for its 32 producer-waves (units [wv*128,(wv+1)*128)); 1 line.
    // BOUNDED spin: failure => wrong answer (absmax), never a wedge.
    if (lane < 32) {
      const int* fp = fl + wv * 32 + lane;
      const int target = s - 1;
      int guard = 0;
      while (ld_flag_cc(fp) < target) {
        if (++guard > (1 << 16)) break;
      }
    }

    // gather this wave's unit range of h_{s-1}: 8 x dwordx4 per lane (8 KiB/wave)
    u32x4 d[8];
#pragma unroll
    for (int jj = 0; jj < 8; ++jj) {
      int local = jj * 64 + lane;
      int row = local >> 5;
      int u0v = wv * 128 + (local & 31) * 4;
      ld_x4_cc(&d[jj], hsrc + (size_t)row * 512 + u0v);
    }
    asm volatile("s_waitcnt vmcnt(0)" ::: "memory");
    __builtin_amdgcn_sched_barrier(0);
#pragma unroll
    for (int jj = 0; jj < 8; ++jj) asm volatile("" : "+v"(d[jj]));
#pragma unroll
    for (int jj = 0; jj < 8; ++jj) {
      int local = jj * 64 + lane;
      int row = local >> 5;
      int u0v = wv * 128 + (local & 31) * 4;
      int kq = u0v >> 3, half = (u0v >> 2) & 1;
      int kqs = (kq & ~7) | ((kq & 7) ^ (row & 7));
      short4_ hh, hl;
#pragma unroll
      for (int i = 0; i < 4; ++i) {
        hh[i] = (short)(d[jj][i] & 0xFFFFu);
        hl[i] = (short)(d[jj][i] >> 16);
      }
      *(short4_*)(Hh + row * 512 + kqs * 8 + half * 4) = hh;
      *(short4_*)(Hl + row * 512 + kqs * 8 + half * 4) = hl;
    }
    __syncthreads();  // collective: MFMA gated on ALL 128 flags transitively

    // MFMA: 3-pass bf16 hi/lo: acc = p + Ah*Bh + Al*Bh + Ah*Bl
    const int br = wv * 16 + wi;
#pragma unroll 4
    for (int ks = 0; ks < 16; ++ks) {
      int kq = ks * 4 + hi4;
      int kqsA = (kq & ~7) | ((kq & 7) ^ (wi & 7));
      int kqsB = (kq & ~7) | ((kq & 7) ^ (br & 7));
      short8 ah = *(const short8*)(Hh + wi * 512 + kqsA * 8);
      short8 al = *(const short8*)(Hl + wi * 512 + kqsA * 8);
      short8 bh = *(const short8*)(WhiL + br * 512 + kqsB * 8);
      short8 bl = *(const short8*)(WloL + br * 512 + kqsB * 8);
      accA = __builtin_amdgcn_mfma_f32_16x16x32_bf16(ah, bh, accA, 0, 0, 0);
      accB = __builtin_amdgcn_mfma_f32_16x16x32_bf16(al, bh, accB, 0, 0, 0);
      accC = __builtin_amdgcn_mfma_f32_16x16x32_bf16(ah, bl, accC, 0, 0, 0);
    }
    __syncthreads();  // all MFMA LDS reads done before next step's staging writes

    // gate combine (quad butterfly, verified r1-r5), pointwise
    const bool qb0 = (q & 1) != 0, qb1 = (q & 2) != 0;
    const int rowloc = hi4 * 4 + q;
    const int b = bg * 16 + rowloc;
    f4 a0;
#pragma unroll
    for (int j = 0; j < 4; ++j) a0[j] = accA[j] + accB[j] + accC[j];
    f4 x1, s1a, s1b, x2a, x2b;
#pragma unroll
    for (int j = 0; j < 4; ++j) x1[j] = __shfl_xor(a0[j], 1);
#pragma unroll
    for (int j = 0; j < 4; ++j) {
      s1a[j] = qb0 ? x1[j] : a0[j];
      s1b[j] = qb0 ? a0[j] : x1[j];
    }
#pragma unroll
    for (int j = 0; j < 4; ++j) {
      x2a[j] = __shfl_xor(s1a[j], 2);
      x2b[j] = __shfl_xor(s1b[j], 2);
    }
    f4 cn, hn;
#pragma unroll
    for (int j = 0; j < 4; ++j) {
      float gi = qb1 ? x2a[j] : s1a[j];
      float gg = qb1 ? s1a[j] : x2a[j];
      float gf = qb1 ? x2b[j] : s1b[j];
      float go = qb1 ? s1b[j] : x2b[j];
      float iv = sigmoidf_(gi);
      float fv = sigmoidf_(gf);
      float gv = tanhf_(gg);
      float ov = sigmoidf_(go);
      float c2 = fv * c_reg[j] + iv * gv;
      cn[j] = c2;
      hn[j] = ov * tanhf_(c2);
    }
    c_reg = cn;
    float s01 = qb0 ? hn[1] : hn[0];
    float s23 = qb0 ? hn[3] : hn[2];
    float hq = qb1 ? s23 : s01;

    // per-wave publish: packed store -> own vmcnt(0) -> own flag (no barrier)
    uint16_t hhi = f2bf(hq);
    uint16_t hlo = f2bf(hq - bf2f(hhi));
    st_u32_cc(hdst + (size_t)b * 512 + u, (uint32_t)hhi | ((uint32_t)hlo << 16));
    asm volatile("s_waitcnt vmcnt(0)" ::: "memory");  // wave's h stores committed
    if (lane == 0) st_flag_cc(myflag, s);
    __builtin_nontemporal_store(hq, &out[(size_t)b * (T_ * H_) + (size_t)(s - 1) * H_ + u]);
  }

  // persist c for chunked launches
  {
    const bool qb0 = (q & 1) != 0, qb1 = (q & 2) != 0;
    const int b = bg * 16 + hi4 * 4 + q;
    float c01 = qb0 ? c_reg[1] : c_reg[0];
    float c23 = qb0 ? c_reg[3] : c_reg[2];
    c_state[(size_t)b * H_ + u] = qb1 ? c23 : c01;
  }
}

extern "C" void kernel_launch(void* const* d_in, const int* in_sizes, int n_in,
                              void* d_out, int out_size, void* d_ws, size_t ws_size,
                              hipStream_t stream) {
  (void)in_sizes; (void)n_in; (void)out_size;
  const int* x = (const int*)d_in[0];
  const float* h0 = (const float*)d_in[1];
  const float* c0 = (const float*)d_in[2];
  const float* emb = (const float*)d_in[3];
  const float* Wih = (const float*)d_in[4];
  const float* Whh = (const float*)d_in[5];
  const float* bih = (const float*)d_in[6];
  const float* bhh = (const float*)d_in[7];
  float* out = (float*)d_out;
  char* ws = (char*)d_ws;

  int* flags = (int*)ws;                          // 2 KiB used (padded to 4 KiB)
  float* c_state = (float*)(ws + 4096);           // 128 KiB
  uint32_t* hP0 = (uint32_t*)(ws + 135168);       // 128 KiB packed h (parity 0)
  uint32_t* hP1 = (uint32_t*)(ws + 266240);       // 128 KiB packed h (parity 1)
  uint16_t* Whi_g = (uint16_t*)(ws + 397312);     // 2 MiB
  uint16_t* Wlo_g = (uint16_t*)(ws + 2494464);    // 2 MiB
  float* pre2 = (float*)(ws + 4591616);           // TB*32*4*1024 fp32

  int TB = 512;
  while (TB > 2 && (size_t)4591616 + (size_t)TB * 524288 > ws_size) TB >>= 1;

  (void)hipFuncSetAttribute(reinterpret_cast<const void*>(k_lstm),
                            hipFuncAttributeMaxDynamicSharedMemorySize, 163840);

  k_prep<<<dim3(4096), dim3(256), 0, stream>>>(Whh, Whi_g, Wlo_g);
  k_init<<<dim3(128), dim3(256), 0, stream>>>(h0, hP0, flags);
  for (int t0 = 0; t0 < 512; t0 += TB) {
    k_pre<<<dim3((TB * 64 / 128) * 16), dim3(256), 0, stream>>>(x, emb, Wih, bih, bhh, pre2, t0);
    k_lstm<<<dim3(128), dim3(256), 163840, stream>>>(pre2, Whi_g, Wlo_g, c0, out, hP0, hP1,
                                                     c_state, flags, t0, TB);
  }
}

// Round 9
// 2317.172 us; speedup vs baseline: 1.4318x; 1.4318x over previous
//
#include <hip/hip_runtime.h>
#include <stdint.h>

typedef __attribute__((ext_vector_type(8))) short short8;
typedef __attribute__((ext_vector_type(4))) short short4_;
typedef __attribute__((ext_vector_type(4))) float f4;
typedef __attribute__((ext_vector_type(4))) uint32_t u32x4;

#define B_ 64
#define T_ 512
#define E_ 512
#define H_ 512
#define GH 2048  // 4*H

static __device__ __forceinline__ uint16_t f2bf(float f) {
  uint32_t u = __builtin_bit_cast(uint32_t, f);
  uint32_t r = (u + 0x7FFFu + ((u >> 16) & 1u)) >> 16;
  return (uint16_t)r;
}
static __device__ __forceinline__ float bf2f(uint16_t b) {
  return __builtin_bit_cast(float, (uint32_t)b << 16);
}
static __device__ __forceinline__ float sigmoidf_(float x) {
  return 1.0f / (1.0f + __expf(-x));
}
static __device__ __forceinline__ float tanhf_(float x) {
  float e = __expf(-2.0f * fabsf(x));
  float t = (1.0f - e) / (1.0f + e);
  return __builtin_copysignf(t, x);
}

// ---- L3-coherent (agent) access helpers: sc0 sc1 = bypass L1+L2, coherence at L3.
// Protocol (r5-proven): producer stores -> vmcnt(0) drain -> barrier -> flag store;
// consumer: poll flags -> (flag seen => data committed) -> batched loads.
// NOTE: any load whose value is consumed must have its s_waitcnt INSIDE the same
// asm block (r8 lesson: separate waitcnt block => compiler may read reg early).
static __device__ __forceinline__ u32x4 ld_flag4_cc(const int* p) {
  u32x4 v;
  asm volatile("global_load_dwordx4 %0, %1, off sc0 sc1\n\ts_waitcnt vmcnt(0)"
               : "=v"(v) : "v"(p) : "memory");
  return v;
}
static __device__ __forceinline__ void ld_x4_cc(u32x4* d, const void* p) {
  asm volatile("global_load_dwordx4 %0, %1, off sc0 sc1" : "=v"(*d) : "v"(p));
}
static __device__ __forceinline__ void st_u32_cc(uint32_t* p, uint32_t v) {
  asm volatile("global_store_dword %0, %1, off sc0 sc1" :: "v"(p), "v"(v) : "memory");
}
static __device__ __forceinline__ void st_flag_cc(int* p, int v) {
  asm volatile("global_store_dword %0, %1, off sc0 sc1" :: "v"(p), "v"(v) : "memory");
}

// ---------------- prep: split W_hh fp32 -> bf16 hi + bf16 lo
__global__ void k_prep(const float* __restrict__ Whh, uint16_t* __restrict__ Whi_g,
                       uint16_t* __restrict__ Wlo_g) {
  int i = blockIdx.x * 256 + threadIdx.x;
  float w = Whh[i];
  uint16_t hi = f2bf(w);
  Whi_g[i] = hi;
  Wlo_g[i] = f2bf(w - bf2f(hi));
}

// ---------------- init: h0 -> packed (hi | lo<<16) parity-0 buffer; zero flags
__global__ void k_init(const float* __restrict__ h0, uint32_t* __restrict__ hP0,
                       int* __restrict__ flags) {
  int i = blockIdx.x * 256 + threadIdx.x;
  if (i < B_ * H_) {
    float v = h0[i];
    uint16_t hi = f2bf(v);
    uint16_t lo = f2bf(v - bf2f(hi));
    hP0[i] = (uint32_t)hi | ((uint32_t)lo << 16);
  }
  if (i < 128) flags[i] = 0;
}

// ---------------- pre-projection GEMM (verified r1-r8). Output: per-consumer blocks
// pre2[((t_rel*32 + ug)*4 + bg)*1024 + g_loc*16 + b_loc], g_loc = q*16 + u_loc.
__launch_bounds__(256)
__global__ void k_pre(const int* __restrict__ x, const float* __restrict__ emb,
                      const float* __restrict__ Wih, const float* __restrict__ bih,
                      const float* __restrict__ bhh, float* __restrict__ pre2, int t0) {
  __shared__ uint16_t As[128 * 64];
  __shared__ uint16_t Bs[128 * 64];
  const int tid = threadIdx.x;
  const int tm = blockIdx.x >> 4;
  const int tn = blockIdx.x & 15;
  const int wid = tid >> 6, lane = tid & 63;
  const int wr = wid >> 1, wc = wid & 1;

  const int arow = tid >> 1;
  const int half = tid & 1;
  const int m = tm * 128 + arow;
  const int bb = m & 63;
  const int tt = t0 + (m >> 6);
  const int xid = x[bb * T_ + tt];
  const float* asrc = emb + (size_t)xid * E_ + half * 32;
  const float* bsrc = Wih + (size_t)(tn * 128 + arow) * E_ + half * 32;

  f4 acc[4][4];
#pragma unroll
  for (int a = 0; a < 4; ++a)
#pragma unroll
    for (int b = 0; b < 4; ++b) acc[a][b] = (f4){0.f, 0.f, 0.f, 0.f};

  for (int kk = 0; kk < 8; ++kk) {
    __syncthreads();
#pragma unroll
    for (int gi = 0; gi < 4; ++gi) {
      f4 a0 = *(const f4*)(asrc + kk * 64 + gi * 8);
      f4 a1 = *(const f4*)(asrc + kk * 64 + gi * 8 + 4);
      f4 b0 = *(const f4*)(bsrc + kk * 64 + gi * 8);
      f4 b1 = *(const f4*)(bsrc + kk * 64 + gi * 8 + 4);
      short8 va, vb;
#pragma unroll
      for (int j = 0; j < 4; ++j) {
        va[j] = (short)f2bf(a0[j]); va[4 + j] = (short)f2bf(a1[j]);
        vb[j] = (short)f2bf(b0[j]); vb[4 + j] = (short)f2bf(b1[j]);
      }
      int kq = half * 4 + gi;
      *(short8*)(As + arow * 64 + (kq ^ (arow & 7)) * 8) = va;
      *(short8*)(Bs + arow * 64 + (kq ^ (arow & 7)) * 8) = vb;
    }
    __syncthreads();
#pragma unroll
    for (int ks = 0; ks < 2; ++ks) {
      short8 af[4], bfr[4];
#pragma unroll
      for (int mi = 0; mi < 4; ++mi) {
        int row = wr * 64 + mi * 16 + (lane & 15);
        int kq = ks * 4 + (lane >> 4);
        af[mi] = *(const short8*)(As + row * 64 + (kq ^ (row & 7)) * 8);
      }
#pragma unroll
      for (int ni = 0; ni < 4; ++ni) {
        int row = wc * 64 + ni * 16 + (lane & 15);
        int kq = ks * 4 + (lane >> 4);
        bfr[ni] = *(const short8*)(Bs + row * 64 + (kq ^ (row & 7)) * 8);
      }
#pragma unroll
      for (int mi = 0; mi < 4; ++mi)
#pragma unroll
        for (int ni = 0; ni < 4; ++ni)
          acc[mi][ni] = __builtin_amdgcn_mfma_f32_16x16x32_bf16(af[mi], bfr[ni], acc[mi][ni], 0, 0, 0);
    }
  }
#pragma unroll
  for (int ni = 0; ni < 4; ++ni) {
    int n = tn * 128 + wc * 64 + ni * 16 + (lane & 15);
    float bias = bih[n] + bhh[n];
    int q = n >> 9, u = n & 511;
    int ug = u >> 4, uloc = u & 15;
    int gl = q * 16 + uloc;
#pragma unroll
    for (int mi = 0; mi < 4; ++mi) {
      int mrow = tm * 128 + wr * 64 + mi * 16 + (lane >> 4) * 4;
      int trel = mrow >> 6;
      int bbr = mrow & 63;
      f4 vst;
#pragma unroll
      for (int j = 0; j < 4; ++j) vst[j] = acc[mi][ni][j] + bias;
      float* dst = pre2 + (((size_t)trel * 32 + ug) * 4 + (bbr >> 4)) * 1024 + gl * 16 + (bbr & 15);
      *(f4*)dst = vst;
    }
  }
}

// ---------------- persistent recurrence: r5-proven per-wg flag protocol with
// packed-u32 h (r7-verified gather/staging) + waitcnt-safe x4 flag poll.
// 128 wgs = 4 bg x 32 ug; 1 wg/CU by LDS capacity (160 KiB). Polls bounded.
__launch_bounds__(256)
__global__ void k_lstm(const float* __restrict__ pre2, const uint16_t* __restrict__ Whi_g,
                       const uint16_t* __restrict__ Wlo_g, const float* __restrict__ c0,
                       float* __restrict__ out, uint32_t* __restrict__ hP0,
                       uint32_t* __restrict__ hP1, float* __restrict__ c_state,
                       int* __restrict__ flags, int t0, int TB) {
  extern __shared__ char smem[];
  uint16_t* WhiL = (uint16_t*)smem;              // [64][512] 64 KiB
  uint16_t* WloL = (uint16_t*)(smem + 65536);    // [64][512] 64 KiB
  uint16_t* Hh   = (uint16_t*)(smem + 131072);   // [16][512] 16 KiB
  uint16_t* Hl   = (uint16_t*)(smem + 147456);   // [16][512] 16 KiB

  const int tid = threadIdx.x;
  const int bg = blockIdx.x & 3;    // batch group (16 rows)
  const int ug = blockIdx.x >> 2;   // unit group (16 units)
  const int wv = tid >> 6, lane = tid & 63;
  const int wi = lane & 15, hi4 = lane >> 4;
  const int q = wi & 3, v = wi >> 2;
  const int u = ug * 16 + wv * 4 + v;   // this lane's unit
  const int gl = q * 16 + wv * 4 + v;   // g_loc in pre2 block

  // stage W hi/lo slice (64 gate-rows x 512) into LDS, 16B-granule XOR swizzle
  for (int it = 0; it < 16; ++it) {
    int gg = it * 256 + tid;
    int r = gg >> 6, kq = gg & 63;
    int grow = (r & 3) * 512 + ug * 16 + (r >> 4) * 4 + ((r >> 2) & 3);
    short8 whi = *(const short8*)(Whi_g + (size_t)grow * 512 + kq * 8);
    short8 wlo = *(const short8*)(Wlo_g + (size_t)grow * 512 + kq * 8);
    int kqs = (kq & ~7) | ((kq & 7) ^ (r & 7));
    *(short8*)(WhiL + r * 512 + kqs * 8) = whi;
    *(short8*)(WloL + r * 512 + kqs * 8) = wlo;
  }

  f4 c_reg;
  {
    const float* csrc = (t0 == 0) ? c0 : c_state;
    const int brow = bg * 16 + hi4 * 4;
#pragma unroll
    for (int j = 0; j < 4; ++j) c_reg[j] = csrc[(size_t)(brow + j) * H_ + u];
  }
  int* fbase = flags + bg * 32;     // 32 per-wg flags (one 128B line)
  int* myflag = fbase + ug;
  __syncthreads();

  for (int s = t0 + 1; s <= t0 + TB; ++s) {
    // bg-local views of the parity double buffer (16 rows x 512 u32 each)
    const uint32_t* hsrc = (((s - 1) & 1) ? hP1 : hP0) + (size_t)bg * 16 * 512;
    uint32_t* hdst = ((s & 1) ? hP1 : hP0) + (size_t)bg * 16 * 512;

    // prefetch this wg's pre2 fragment (wg-private, plain L2 load)
    f4 accA, accB, accC;
    {
      const float* pblk = pre2 + (((size_t)(s - 1 - t0) * 32 + ug) * 4 + bg) * 1024;
      accA = *(const f4*)(pblk + gl * 16 + hi4 * 4);
      accB = (f4){0.f, 0.f, 0.f, 0.f};
      accC = accB;
    }

    // poll all 32 sibling wg-flags: lanes 0..7 each load 4 flags (waitcnt-safe),
    // whole-wave ballot. BOUNDED: failure => wrong answer (absmax), never a wedge.
    {
      const int target = s - 1;
      int guard = 0;
      bool ok;
      do {
        ok = true;
        if (lane < 8) {
          u32x4 fv = ld_flag4_cc(fbase + lane * 4);
          ok = (int)fv[0] >= target && (int)fv[1] >= target &&
               (int)fv[2] >= target && (int)fv[3] >= target;
        }
        if (!__all(ok)) __builtin_amdgcn_s_sleep(1);
        if (++guard > (1 << 17)) break;
      } while (!__all(ok));
    }

    // gather this wave's unit range of h_{s-1}: 8 x dwordx4 per lane (r7-verified)
    u32x4 d[8];
#pragma unroll
    for (int jj = 0; jj < 8; ++jj) {
      int local = jj * 64 + lane;
      int row = local >> 5;
      int u0v = wv * 128 + (local & 31) * 4;
      ld_x4_cc(&d[jj], hsrc + (size_t)row * 512 + u0v);
    }
    asm volatile("s_waitcnt vmcnt(0)" ::: "memory");
    __builtin_amdgcn_sched_barrier(0);
#pragma unroll
    for (int jj = 0; jj < 8; ++jj) asm volatile("" : "+v"(d[jj]));
#pragma unroll
    for (int jj = 0; jj < 8; ++jj) {
      int local = jj * 64 + lane;
      int row = local >> 5;
      int u0v = wv * 128 + (local & 31) * 4;
      int kq = u0v >> 3, half = (u0v >> 2) & 1;
      int kqs = (kq & ~7) | ((kq & 7) ^ (row & 7));
      short4_ hh, hl;
#pragma unroll
      for (int i = 0; i < 4; ++i) {
        hh[i] = (short)(d[jj][i] & 0xFFFFu);
        hl[i] = (short)(d[jj][i] >> 16);
      }
      *(short4_*)(Hh + row * 512 + kqs * 8 + half * 4) = hh;
      *(short4_*)(Hl + row * 512 + kqs * 8 + half * 4) = hl;
    }
    __syncthreads();  // staging barrier: all h staged before MFMA

    // MFMA: 3-pass bf16 hi/lo: acc = p + Ah*Bh + Al*Bh + Ah*Bl
    const int br = wv * 16 + wi;
#pragma unroll 4
    for (int ks = 0; ks < 16; ++ks) {
      int kq = ks * 4 + hi4;
      int kqsA = (kq & ~7) | ((kq & 7) ^ (wi & 7));
      int kqsB = (kq & ~7) | ((kq & 7) ^ (br & 7));
      short8 ah = *(const short8*)(Hh + wi * 512 + kqsA * 8);
      short8 al = *(const short8*)(Hl + wi * 512 + kqsA * 8);
      short8 bh = *(const short8*)(WhiL + br * 512 + kqsB * 8);
      short8 bl = *(const short8*)(WloL + br * 512 + kqsB * 8);
      accA = __builtin_amdgcn_mfma_f32_16x16x32_bf16(ah, bh, accA, 0, 0, 0);
      accB = __builtin_amdgcn_mfma_f32_16x16x32_bf16(al, bh, accB, 0, 0, 0);
      accC = __builtin_amdgcn_mfma_f32_16x16x32_bf16(ah, bl, accC, 0, 0, 0);
    }

    // gate combine (quad butterfly, verified r1-r7), pointwise
    const bool qb0 = (q & 1) != 0, qb1 = (q & 2) != 0;
    const int rowloc = hi4 * 4 + q;       // local batch row within this bg
    const int b = bg * 16 + rowloc;       // global batch row
    f4 a0;
#pragma unroll
    for (int j = 0; j < 4; ++j) a0[j] = accA[j] + accB[j] + accC[j];
    f4 x1, s1a, s1b, x2a, x2b;
#pragma unroll
    for (int j = 0; j < 4; ++j) x1[j] = __shfl_xor(a0[j], 1);
#pragma unroll
    for (int j = 0; j < 4; ++j) {
      s1a[j] = qb0 ? x1[j] : a0[j];
      s1b[j] = qb0 ? a0[j] : x1[j];
    }
#pragma unroll
    for (int j = 0; j < 4; ++j) {
      x2a[j] = __shfl_xor(s1a[j], 2);
      x2b[j] = __shfl_xor(s1b[j], 2);
    }
    f4 cn, hn;
#pragma unroll
    for (int j = 0; j < 4; ++j) {
      float gi = qb1 ? x2a[j] : s1a[j];
      float gg = qb1 ? s1a[j] : x2a[j];
      float gf = qb1 ? x2b[j] : s1b[j];
      float go = qb1 ? s1b[j] : x2b[j];
      float iv = sigmoidf_(gi);
      float fv = sigmoidf_(gf);
      float gv = tanhf_(gg);
      float ov = sigmoidf_(go);
      float c2 = fv * c_reg[j] + iv * gv;
      cn[j] = c2;
      hn[j] = ov * tanhf_(c2);
    }
    c_reg = cn;
    float s01 = qb0 ? hn[1] : hn[0];
    float s23 = qb0 ? hn[3] : hn[2];
    float hq = qb1 ? s23 : s01;

    // publish (r5 protocol): packed store at LOCAL row -> drain -> barrier -> flag
    uint16_t hhi = f2bf(hq);
    uint16_t hlo = f2bf(hq - bf2f(hhi));
    st_u32_cc(hdst + (size_t)rowloc * 512 + u, (uint32_t)hhi | ((uint32_t)hlo << 16));
    asm volatile("s_waitcnt vmcnt(0)" ::: "memory");  // all waves' h at L3
    __syncthreads();                                   // (also protects Hh/Hl reuse)
    if (tid == 0) st_flag_cc(myflag, s);
    __builtin_nontemporal_store(hq, &out[(size_t)b * (T_ * H_) + (size_t)(s - 1) * H_ + u]);
  }

  // persist c for chunked launches
  {
    const bool qb0 = (q & 1) != 0, qb1 = (q & 2) != 0;
    const int b = bg * 16 + hi4 * 4 + q;
    float c01 = qb0 ? c_reg[1] : c_reg[0];
    float c23 = qb0 ? c_reg[3] : c_reg[2];
    c_state[(size_t)b * H_ + u] = qb1 ? c23 : c01;
  }
}

extern "C" void kernel_launch(void* const* d_in, const int* in_sizes, int n_in,
                              void* d_out, int out_size, void* d_ws, size_t ws_size,
                              hipStream_t stream) {
  (void)in_sizes; (void)n_in; (void)out_size;
  const int* x = (const int*)d_in[0];
  const float* h0 = (const float*)d_in[1];
  const float* c0 = (const float*)d_in[2];
  const float* emb = (const float*)d_in[3];
  const float* Wih = (const float*)d_in[4];
  const float* Whh = (const float*)d_in[5];
  const float* bih = (const float*)d_in[6];
  const float* bhh = (const float*)d_in[7];
  float* out = (float*)d_out;
  char* ws = (char*)d_ws;

  int* flags = (int*)ws;                          // 512 B used (padded to 4 KiB)
  float* c_state = (float*)(ws + 4096);           // 128 KiB
  uint32_t* hP0 = (uint32_t*)(ws + 135168);       // 128 KiB packed h (parity 0)
  uint32_t* hP1 = (uint32_t*)(ws + 266240);       // 128 KiB packed h (parity 1)
  uint16_t* Whi_g = (uint16_t*)(ws + 397312);     // 2 MiB
  uint16_t* Wlo_g = (uint16_t*)(ws + 2494464);    // 2 MiB
  float* pre2 = (float*)(ws + 4591616);           // TB*32*4*1024 fp32

  int TB = 512;
  while (TB > 2 && (size_t)4591616 + (size_t)TB * 524288 > ws_size) TB >>= 1;

  (void)hipFuncSetAttribute(reinterpret_cast<const void*>(k_lstm),
                            hipFuncAttributeMaxDynamicSharedMemorySize, 163840);

  k_prep<<<dim3(4096), dim3(256), 0, stream>>>(Whh, Whi_g, Wlo_g);
  k_init<<<dim3(128), dim3(256), 0, stream>>>(h0, hP0, flags);
  for (int t0 = 0; t0 < 512; t0 += TB) {
    k_pre<<<dim3((TB * 64 / 128) * 16), dim3(256), 0, stream>>>(x, emb, Wih, bih, bhh, pre2, t0);
    k_lstm<<<dim3(128), dim3(256), 163840, stream>>>(pre2, Whi_g, Wlo_g, c0, out, hP0, hP1,
                                                     c_state, flags, t0, TB);
  }
}

// Round 10
// 2300.172 us; speedup vs baseline: 1.4424x; 1.0074x over previous
//
#include <hip/hip_runtime.h>
#include <stdint.h>

typedef __attribute__((ext_vector_type(8))) short short8;
typedef __attribute__((ext_vector_type(4))) short short4_;
typedef __attribute__((ext_vector_type(4))) float f4;
typedef __attribute__((ext_vector_type(4))) uint32_t u32x4;

#define B_ 64
#define T_ 512
#define E_ 512
#define H_ 512
#define GH 2048  // 4*H

static __device__ __forceinline__ uint16_t f2bf(float f) {
  uint32_t u = __builtin_bit_cast(uint32_t, f);
  uint32_t r = (u + 0x7FFFu + ((u >> 16) & 1u)) >> 16;
  return (uint16_t)r;
}
static __device__ __forceinline__ float bf2f(uint16_t b) {
  return __builtin_bit_cast(float, (uint32_t)b << 16);
}
static __device__ __forceinline__ float sigmoidf_(float x) {
  return 1.0f / (1.0f + __expf(-x));
}
static __device__ __forceinline__ float tanhf_(float x) {
  float e = __expf(-2.0f * fabsf(x));
  float t = (1.0f - e) / (1.0f + e);
  return __builtin_copysignf(t, x);
}

// ---- L3-coherent (agent) access helpers: sc0 sc1 = bypass L1+L2, coherence at L3.
// Protocol (r5/r9-proven): producer stores -> vmcnt(0) drain -> barrier -> flag;
// consumer: poll flags -> (flag seen => data committed) -> batched loads.
// Rule: a load whose value is consumed must have its s_waitcnt INSIDE the same
// asm block, or be covered by an explicit vmcnt(0)+sched_barrier+retie (r8 lesson).
static __device__ __forceinline__ u32x4 ld_flag4_cc(const int* p) {
  u32x4 v;
  asm volatile("global_load_dwordx4 %0, %1, off sc0 sc1\n\ts_waitcnt vmcnt(0)"
               : "=v"(v) : "v"(p) : "memory");
  return v;
}
static __device__ __forceinline__ void ld_x4_cc(u32x4* d, const void* p) {
  asm volatile("global_load_dwordx4 %0, %1, off sc0 sc1" : "=v"(*d) : "v"(p));
}
static __device__ __forceinline__ void st_u32_cc(uint32_t* p, uint32_t v) {
  asm volatile("global_store_dword %0, %1, off sc0 sc1" :: "v"(p), "v"(v) : "memory");
}
static __device__ __forceinline__ void st_flag_cc(int* p, int v) {
  asm volatile("global_store_dword %0, %1, off sc0 sc1" :: "v"(p), "v"(v) : "memory");
}

// ---------------- prep: split W_hh fp32 -> bf16 hi + bf16 lo
__global__ void k_prep(const float* __restrict__ Whh, uint16_t* __restrict__ Whi_g,
                       uint16_t* __restrict__ Wlo_g) {
  int i = blockIdx.x * 256 + threadIdx.x;
  float w = Whh[i];
  uint16_t hi = f2bf(w);
  Whi_g[i] = hi;
  Wlo_g[i] = f2bf(w - bf2f(hi));
}

// ---------------- init: h0 -> packed (hi | lo<<16) parity-0 buffer; zero flags
__global__ void k_init(const float* __restrict__ h0, uint32_t* __restrict__ hP0,
                       int* __restrict__ flags) {
  int i = blockIdx.x * 256 + threadIdx.x;
  if (i < B_ * H_) {
    float v = h0[i];
    uint16_t hi = f2bf(v);
    uint16_t lo = f2bf(v - bf2f(hi));
    hP0[i] = (uint32_t)hi | ((uint32_t)lo << 16);
  }
  if (i < 128) flags[i] = 0;
}

// ---------------- pre-projection GEMM (verified r1-r9). Output: per-consumer blocks
// pre2[((t_rel*32 + ug)*4 + bg)*1024 + g_loc*16 + b_loc], g_loc = q*16 + u_loc.
// Epilogue stores NONTEMPORAL: pre2 is read-once by k_lstm (keep caches clean).
__launch_bounds__(256)
__global__ void k_pre(const int* __restrict__ x, const float* __restrict__ emb,
                      const float* __restrict__ Wih, const float* __restrict__ bih,
                      const float* __restrict__ bhh, float* __restrict__ pre2, int t0) {
  __shared__ uint16_t As[128 * 64];
  __shared__ uint16_t Bs[128 * 64];
  const int tid = threadIdx.x;
  const int tm = blockIdx.x >> 4;
  const int tn = blockIdx.x & 15;
  const int wid = tid >> 6, lane = tid & 63;
  const int wr = wid >> 1, wc = wid & 1;

  const int arow = tid >> 1;
  const int half = tid & 1;
  const int m = tm * 128 + arow;
  const int bb = m & 63;
  const int tt = t0 + (m >> 6);
  const int xid = x[bb * T_ + tt];
  const float* asrc = emb + (size_t)xid * E_ + half * 32;
  const float* bsrc = Wih + (size_t)(tn * 128 + arow) * E_ + half * 32;

  f4 acc[4][4];
#pragma unroll
  for (int a = 0; a < 4; ++a)
#pragma unroll
    for (int b = 0; b < 4; ++b) acc[a][b] = (f4){0.f, 0.f, 0.f, 0.f};

  for (int kk = 0; kk < 8; ++kk) {
    __syncthreads();
#pragma unroll
    for (int gi = 0; gi < 4; ++gi) {
      f4 a0 = *(const f4*)(asrc + kk * 64 + gi * 8);
      f4 a1 = *(const f4*)(asrc + kk * 64 + gi * 8 + 4);
      f4 b0 = *(const f4*)(bsrc + kk * 64 + gi * 8);
      f4 b1 = *(const f4*)(bsrc + kk * 64 + gi * 8 + 4);
      short8 va, vb;
#pragma unroll
      for (int j = 0; j < 4; ++j) {
        va[j] = (short)f2bf(a0[j]); va[4 + j] = (short)f2bf(a1[j]);
        vb[j] = (short)f2bf(b0[j]); vb[4 + j] = (short)f2bf(b1[j]);
      }
      int kq = half * 4 + gi;
      *(short8*)(As + arow * 64 + (kq ^ (arow & 7)) * 8) = va;
      *(short8*)(Bs + arow * 64 + (kq ^ (arow & 7)) * 8) = vb;
    }
    __syncthreads();
#pragma unroll
    for (int ks = 0; ks < 2; ++ks) {
      short8 af[4], bfr[4];
#pragma unroll
      for (int mi = 0; mi < 4; ++mi) {
        int row = wr * 64 + mi * 16 + (lane & 15);
        int kq = ks * 4 + (lane >> 4);
        af[mi] = *(const short8*)(As + row * 64 + (kq ^ (row & 7)) * 8);
      }
#pragma unroll
      for (int ni = 0; ni < 4; ++ni) {
        int row = wc * 64 + ni * 16 + (lane & 15);
        int kq = ks * 4 + (lane >> 4);
        bfr[ni] = *(const short8*)(Bs + row * 64 + (kq ^ (row & 7)) * 8);
      }
#pragma unroll
      for (int mi = 0; mi < 4; ++mi)
#pragma unroll
        for (int ni = 0; ni < 4; ++ni)
          acc[mi][ni] = __builtin_amdgcn_mfma_f32_16x16x32_bf16(af[mi], bfr[ni], acc[mi][ni], 0, 0, 0);
    }
  }
#pragma unroll
  for (int ni = 0; ni < 4; ++ni) {
    int n = tn * 128 + wc * 64 + ni * 16 + (lane & 15);
    float bias = bih[n] + bhh[n];
    int q = n >> 9, u = n & 511;
    int ug = u >> 4, uloc = u & 15;
    int gl = q * 16 + uloc;
#pragma unroll
    for (int mi = 0; mi < 4; ++mi) {
      int mrow = tm * 128 + wr * 64 + mi * 16 + (lane >> 4) * 4;
      int trel = mrow >> 6;
      int bbr = mrow & 63;
      f4 vst;
#pragma unroll
      for (int j = 0; j < 4; ++j) vst[j] = acc[mi][ni][j] + bias;
      float* dst = pre2 + (((size_t)trel * 32 + ug) * 4 + (bbr >> 4)) * 1024 + gl * 16 + (bbr & 15);
      __builtin_nontemporal_store(vst, (f4*)dst);
    }
  }
}

// ---------------- persistent recurrence: r9-proven protocol + L3-hygiene (nt pre2
// loads), early-poll overlapped with publish drain, 6x8 MFMA chains.
// 128 wgs = 4 bg x 32 ug; 1 wg/CU by LDS capacity (160 KiB). Polls bounded.
__launch_bounds__(256)
__global__ void k_lstm(const float* __restrict__ pre2, const uint16_t* __restrict__ Whi_g,
                       const uint16_t* __restrict__ Wlo_g, const float* __restrict__ c0,
                       float* __restrict__ out, uint32_t* __restrict__ hP0,
                       uint32_t* __restrict__ hP1, float* __restrict__ c_state,
                       int* __restrict__ flags, int t0, int TB) {
  extern __shared__ char smem[];
  uint16_t* WhiL = (uint16_t*)smem;              // [64][512] 64 KiB
  uint16_t* WloL = (uint16_t*)(smem + 65536);    // [64][512] 64 KiB
  uint16_t* Hh   = (uint16_t*)(smem + 131072);   // [16][512] 16 KiB
  uint16_t* Hl   = (uint16_t*)(smem + 147456);   // [16][512] 16 KiB

  const int tid = threadIdx.x;
  const int bg = blockIdx.x & 3;    // batch group (16 rows)
  const int ug = blockIdx.x >> 2;   // unit group (16 units)
  const int wv = tid >> 6, lane = tid & 63;
  const int wi = lane & 15, hi4 = lane >> 4;
  const int q = wi & 3, v = wi >> 2;
  const int u = ug * 16 + wv * 4 + v;   // this lane's unit
  const int gl = q * 16 + wv * 4 + v;   // g_loc in pre2 block

  // stage W hi/lo slice (64 gate-rows x 512) into LDS, 16B-granule XOR swizzle
  for (int it = 0; it < 16; ++it) {
    int gg = it * 256 + tid;
    int r = gg >> 6, kq = gg & 63;
    int grow = (r & 3) * 512 + ug * 16 + (r >> 4) * 4 + ((r >> 2) & 3);
    short8 whi = *(const short8*)(Whi_g + (size_t)grow * 512 + kq * 8);
    short8 wlo = *(const short8*)(Wlo_g + (size_t)grow * 512 + kq * 8);
    int kqs = (kq & ~7) | ((kq & 7) ^ (r & 7));
    *(short8*)(WhiL + r * 512 + kqs * 8) = whi;
    *(short8*)(WloL + r * 512 + kqs * 8) = wlo;
  }

  f4 c_reg;
  {
    const float* csrc = (t0 == 0) ? c0 : c_state;
    const int brow = bg * 16 + hi4 * 4;
#pragma unroll
    for (int j = 0; j < 4; ++j) c_reg[j] = csrc[(size_t)(brow + j) * H_ + u];
  }
  int* fbase = flags + bg * 32;     // 32 per-wg flags (one 128B line)
  int* myflag = fbase + ug;
  u32x4 fv0 = (u32x4){0, 0, 0, 0}; // early-poll carry (0 => under-report => safe)
  __syncthreads();

  for (int s = t0 + 1; s <= t0 + TB; ++s) {
    // bg-local views of the parity double buffer (16 rows x 512 u32 each)
    const uint32_t* hsrc = (((s - 1) & 1) ? hP1 : hP0) + (size_t)bg * 16 * 512;
    uint32_t* hdst = ((s & 1) ? hP1 : hP0) + (size_t)bg * 16 * 512;

    // prefetch this wg's pre2 fragment — NONTEMPORAL (read-once; don't evict
    // the h/flag working set from L3)
    f4 accA, accB, accC;
    {
      const f4* pp = (const f4*)(pre2 + (((size_t)(s - 1 - t0) * 32 + ug) * 4 + bg) * 1024 +
                                 gl * 16 + hi4 * 4);
      accA = __builtin_nontemporal_load(pp);
      accB = (f4){0.f, 0.f, 0.f, 0.f};
      accC = accB;
    }

    // poll all 32 sibling wg-flags; round 0 = fv0 (issued during last publish
    // drain). Flags monotonic => stale fv0 only under-reports. BOUNDED.
    {
      const int target = s - 1;
      bool ok = true;
      if (lane < 8)
        ok = (int)fv0[0] >= target && (int)fv0[1] >= target &&
             (int)fv0[2] >= target && (int)fv0[3] >= target;
      int guard = 0;
      while (!__all(ok)) {
        __builtin_amdgcn_s_sleep(1);
        ok = true;
        if (lane < 8) {
          u32x4 fv = ld_flag4_cc(fbase + lane * 4);
          ok = (int)fv[0] >= target && (int)fv[1] >= target &&
               (int)fv[2] >= target && (int)fv[3] >= target;
        }
        if (++guard > (1 << 17)) break;
      }
    }

    // gather this wave's unit range of h_{s-1}: 8 x dwordx4 per lane (r7-verified)
    u32x4 d[8];
#pragma unroll
    for (int jj = 0; jj < 8; ++jj) {
      int local = jj * 64 + lane;
      int row = local >> 5;
      int u0v = wv * 128 + (local & 31) * 4;
      ld_x4_cc(&d[jj], hsrc + (size_t)row * 512 + u0v);
    }
    asm volatile("s_waitcnt vmcnt(0)" ::: "memory");
    __builtin_amdgcn_sched_barrier(0);
#pragma unroll
    for (int jj = 0; jj < 8; ++jj) asm volatile("" : "+v"(d[jj]));
#pragma unroll
    for (int jj = 0; jj < 8; ++jj) {
      int local = jj * 64 + lane;
      int row = local >> 5;
      int u0v = wv * 128 + (local & 31) * 4;
      int kq = u0v >> 3, half = (u0v >> 2) & 1;
      int kqs = (kq & ~7) | ((kq & 7) ^ (row & 7));
      short4_ hh, hl;
#pragma unroll
      for (int i = 0; i < 4; ++i) {
        hh[i] = (short)(d[jj][i] & 0xFFFFu);
        hl[i] = (short)(d[jj][i] >> 16);
      }
      *(short4_*)(Hh + row * 512 + kqs * 8 + half * 4) = hh;
      *(short4_*)(Hl + row * 512 + kqs * 8 + half * 4) = hl;
    }
    __syncthreads();  // staging barrier: all h staged before MFMA

    // MFMA: 3-pass bf16 hi/lo in 6 chains of 8 (halved dependent latency):
    // total = p + Ah*Bh + Al*Bh + Ah*Bl
    f4 accA2 = (f4){0.f, 0.f, 0.f, 0.f}, accB2 = accA2, accC2 = accA2;
    const int br = wv * 16 + wi;
#pragma unroll
    for (int ks2 = 0; ks2 < 8; ++ks2) {
#pragma unroll
      for (int p = 0; p < 2; ++p) {
        int ks = ks2 * 2 + p;
        int kq = ks * 4 + hi4;
        int kqsA = (kq & ~7) | ((kq & 7) ^ (wi & 7));
        int kqsB = (kq & ~7) | ((kq & 7) ^ (br & 7));
        short8 ah = *(const short8*)(Hh + wi * 512 + kqsA * 8);
        short8 al = *(const short8*)(Hl + wi * 512 + kqsA * 8);
        short8 bh = *(const short8*)(WhiL + br * 512 + kqsB * 8);
        short8 bl = *(const short8*)(WloL + br * 512 + kqsB * 8);
        if (p == 0) {
          accA = __builtin_amdgcn_mfma_f32_16x16x32_bf16(ah, bh, accA, 0, 0, 0);
          accB = __builtin_amdgcn_mfma_f32_16x16x32_bf16(al, bh, accB, 0, 0, 0);
          accC = __builtin_amdgcn_mfma_f32_16x16x32_bf16(ah, bl, accC, 0, 0, 0);
        } else {
          accA2 = __builtin_amdgcn_mfma_f32_16x16x32_bf16(ah, bh, accA2, 0, 0, 0);
          accB2 = __builtin_amdgcn_mfma_f32_16x16x32_bf16(al, bh, accB2, 0, 0, 0);
          accC2 = __builtin_amdgcn_mfma_f32_16x16x32_bf16(ah, bl, accC2, 0, 0, 0);
        }
      }
    }

    // gate combine (quad butterfly, verified r1-r9), pointwise
    const bool qb0 = (q & 1) != 0, qb1 = (q & 2) != 0;
    const int rowloc = hi4 * 4 + q;       // local batch row within this bg
    const int b = bg * 16 + rowloc;       // global batch row
    f4 a0;
#pragma unroll
    for (int j = 0; j < 4; ++j)
      a0[j] = (accA[j] + accA2[j]) + (accB[j] + accB2[j]) + (accC[j] + accC2[j]);
    f4 x1, s1a, s1b, x2a, x2b;
#pragma unroll
    for (int j = 0; j < 4; ++j) x1[j] = __shfl_xor(a0[j], 1);
#pragma unroll
    for (int j = 0; j < 4; ++j) {
      s1a[j] = qb0 ? x1[j] : a0[j];
      s1b[j] = qb0 ? a0[j] : x1[j];
    }
#pragma unroll
    for (int j = 0; j < 4; ++j) {
      x2a[j] = __shfl_xor(s1a[j], 2);
      x2b[j] = __shfl_xor(s1b[j], 2);
    }
    f4 cn, hn;
#pragma unroll
    for (int j = 0; j < 4; ++j) {
      float gi = qb1 ? x2a[j] : s1a[j];
      float gg = qb1 ? s1a[j] : x2a[j];
      float gf = qb1 ? x2b[j] : s1b[j];
      float go = qb1 ? s1b[j] : x2b[j];
      float iv = sigmoidf_(gi);
      float fv = sigmoidf_(gf);
      float gv = tanhf_(gg);
      float ov = sigmoidf_(go);
      float c2 = fv * c_reg[j] + iv * gv;
      cn[j] = c2;
      hn[j] = ov * tanhf_(c2);
    }
    c_reg = cn;
    float s01 = qb0 ? hn[1] : hn[0];
    float s23 = qb0 ? hn[3] : hn[2];
    float hq = qb1 ? s23 : s01;

    // publish (r5/r9 protocol) + EARLY POLL for next step overlapped with the
    // drain: store h -> issue flag-line loads -> vmcnt(0) (drains both) ->
    // retie -> barrier -> tid0 flag -> out store.
    uint16_t hhi = f2bf(hq);
    uint16_t hlo = f2bf(hq - bf2f(hhi));
    st_u32_cc(hdst + (size_t)rowloc * 512 + u, (uint32_t)hhi | ((uint32_t)hlo << 16));
    if (lane < 8) ld_x4_cc(&fv0, fbase + lane * 4);
    asm volatile("s_waitcnt vmcnt(0)" ::: "memory");  // h store committed (+ poll loads)
    __builtin_amdgcn_sched_barrier(0);
    asm volatile("" : "+v"(fv0));
    __syncthreads();                                   // all waves drained; Hh/Hl reusable
    if (tid == 0) st_flag_cc(myflag, s);
    __builtin_nontemporal_store(hq, &out[(size_t)b * (T_ * H_) + (size_t)(s - 1) * H_ + u]);
  }

  // persist c for chunked launches
  {
    const bool qb0 = (q & 1) != 0, qb1 = (q & 2) != 0;
    const int b = bg * 16 + hi4 * 4 + q;
    float c01 = qb0 ? c_reg[1] : c_reg[0];
    float c23 = qb0 ? c_reg[3] : c_reg[2];
    c_state[(size_t)b * H_ + u] = qb1 ? c23 : c01;
  }
}

extern "C" void kernel_launch(void* const* d_in, const int* in_sizes, int n_in,
                              void* d_out, int out_size, void* d_ws, size_t ws_size,
                              hipStream_t stream) {
  (void)in_sizes; (void)n_in; (void)out_size;
  const int* x = (const int*)d_in[0];
  const float* h0 = (const float*)d_in[1];
  const float* c0 = (const float*)d_in[2];
  const float* emb = (const float*)d_in[3];
  const float* Wih = (const float*)d_in[4];
  const float* Whh = (const float*)d_in[5];
  const float* bih = (const float*)d_in[6];
  const float* bhh = (const float*)d_in[7];
  float* out = (float*)d_out;
  char* ws = (char*)d_ws;

  int* flags = (int*)ws;                          // 512 B used (padded to 4 KiB)
  float* c_state = (float*)(ws + 4096);           // 128 KiB
  uint32_t* hP0 = (uint32_t*)(ws + 135168);       // 128 KiB packed h (parity 0)
  uint32_t* hP1 = (uint32_t*)(ws + 266240);       // 128 KiB packed h (parity 1)
  uint16_t* Whi_g = (uint16_t*)(ws + 397312);     // 2 MiB
  uint16_t* Wlo_g = (uint16_t*)(ws + 2494464);    // 2 MiB
  float* pre2 = (float*)(ws + 4591616);           // TB*32*4*1024 fp32

  int TB = 512;
  while (TB > 2 && (size_t)4591616 + (size_t)TB * 524288 > ws_size) TB >>= 1;

  (void)hipFuncSetAttribute(reinterpret_cast<const void*>(k_lstm),
                            hipFuncAttributeMaxDynamicSharedMemorySize, 163840);

  k_prep<<<dim3(4096), dim3(256), 0, stream>>>(Whh, Whi_g, Wlo_g);
  k_init<<<dim3(128), dim3(256), 0, stream>>>(h0, hP0, flags);
  for (int t0 = 0; t0 < 512; t0 += TB) {
    k_pre<<<dim3((TB * 64 / 128) * 16), dim3(256), 0, stream>>>(x, emb, Wih, bih, bhh, pre2, t0);
    k_lstm<<<dim3(128), dim3(256), 163840, stream>>>(pre2, Whi_g, Wlo_g, c0, out, hP0, hP1,
                                                     c_state, flags, t0, TB);
  }
}